// Round 3
// baseline (485.288 us; speedup 1.0000x reference)
//
#include <hip/hip_runtime.h>
#include <hip/hip_bf16.h>

#define B_ 32
#define T_ 1000
#define H_ 512
#define V_ 2048
#define L_ 100
#define M_ (B_*T_)          // 32000 rows
#define GSTRIDE 104         // p_ext row stride (floats): [0]=blank, [2+l]=label l
#define LOG2E 1.4426950408889634f
#define LSE_SHIFT 48.0f

typedef __attribute__((ext_vector_type(8))) short bf16x8;
typedef __attribute__((ext_vector_type(4))) float f32x4;

#define AS_G(p)  ((const __attribute__((address_space(1))) unsigned int*)(p))
#define AS_L(p)  ((__attribute__((address_space(3))) unsigned int*)(p))

__device__ __forceinline__ unsigned short f2bf(float x) {
    unsigned int u; __builtin_memcpy(&u, &x, 4);
    unsigned int r = (u + 0x7fffu + ((u >> 16) & 1u)) >> 16;   // RNE
    return (unsigned short)r;
}

// DPP helpers (gfx9-lineage DPP retained on CDNA4).
// wave_shr:1 = 0x138; row_shr:N = 0x110+N; bcast15=0x142; bcast31=0x143.
__device__ __forceinline__ float dpp_shr1(float x) {          // lane i <- lane i-1, lane0 <- 0
    int r = __builtin_amdgcn_update_dpp(0, __builtin_bit_cast(int, x), 0x138, 0xf, 0xf, false);
    return __builtin_bit_cast(float, r);
}
template<int CTRL>
__device__ __forceinline__ float fmax_dpp(float x) {          // zero-fill ok: operands >= 0
    int s = __builtin_amdgcn_update_dpp(0, __builtin_bit_cast(int, x), CTRL, 0xf, 0xf, false);
    return fmaxf(x, __builtin_bit_cast(float, s));
}
__device__ __forceinline__ float wave_max_nonneg(float x) {   // max over 64 lanes, broadcast
    x = fmax_dpp<0x111>(x);
    x = fmax_dpp<0x112>(x);
    x = fmax_dpp<0x114>(x);
    x = fmax_dpp<0x118>(x);
    x = fmax_dpp<0x142>(x);   // lane31 = max(0..31), lane63 = max(32..63)
    x = fmax_dpp<0x143>(x);   // lane63 = max(all)
    return __builtin_bit_cast(float, __builtin_amdgcn_readlane(__builtin_bit_cast(int, x), 63));
}

// ---------------------------------------------------------------------------
// Kernel 0: zero out + Srow, convert eouts/W fp32 -> bf16 into ws
// ---------------------------------------------------------------------------
__global__ __launch_bounds__(256) void prep_kernel(
        const float* __restrict__ eouts, const float* __restrict__ W,
        unsigned short* __restrict__ eb, unsigned short* __restrict__ wb,
        float* __restrict__ Srow, float* __restrict__ out)
{
    const int E4 = M_*H_/4;      // 4,096,000
    const int W4 = V_*H_/4;      //   262,144
    const int S4 = M_/4;         //     8,000
    int idx = blockIdx.x*256 + threadIdx.x;
    if (idx == 0) out[0] = 0.f;
    if (idx < E4) {
        float4 v = ((const float4*)eouts)[idx];
        ushort4 o; o.x=f2bf(v.x); o.y=f2bf(v.y); o.z=f2bf(v.z); o.w=f2bf(v.w);
        ((ushort4*)eb)[idx] = o;
    } else if (idx < E4 + W4) {
        int j = idx - E4;
        float4 v = ((const float4*)W)[j];
        ushort4 o; o.x=f2bf(v.x); o.y=f2bf(v.y); o.z=f2bf(v.z); o.w=f2bf(v.w);
        ((ushort4*)wb)[j] = o;
    } else if (idx < E4 + W4 + S4) {
        int j = idx - E4 - W4;
        ((float4*)Srow)[j] = make_float4(0.f,0.f,0.f,0.f);
    }
}

// ---------------------------------------------------------------------------
// Kernel 1: m97-style bf16 MFMA GEMM (logits = eouts @ W^T + b) fused with
// row-wise sum of 2^(z*log2e - 48). 128x128 tile, BK=64, global_load_lds x16.
// ---------------------------------------------------------------------------
__global__ __launch_bounds__(256) void gemm_lse_kernel(
        const unsigned short* __restrict__ eb, const unsigned short* __restrict__ wb,
        const float* __restrict__ bias, float* __restrict__ Srow)
{
    __shared__ __align__(16) unsigned short As[128*64];   // unpadded: global_load_lds layout
    __shared__ __align__(16) unsigned short Bs[128*64];
    __shared__ float rs[128];
    const int tid  = threadIdx.x;
    const int w    = tid >> 6;
    const int lane = tid & 63;
    const int m    = lane & 15;
    const int q    = lane >> 4;
    const int wrow = w >> 1;
    const int wcol = w & 1;
    const int nbase = blockIdx.x * 128;
    const int mbase = blockIdx.y * 128;
    if (tid < 128) rs[tid] = 0.f;

    const int rbase = w*32 + (lane >> 3);   // staging row (+j*8)
    const int k8    = (lane & 7) * 8;       // staging k offset (shorts)

    f32x4 acc[4][4];
    #pragma unroll
    for (int i=0;i<4;i++)
        #pragma unroll
        for (int j=0;j<4;j++) acc[i][j] = (f32x4){0.f,0.f,0.f,0.f};

    for (int kc = 0; kc < 8; ++kc) {
        __syncthreads();
        #pragma unroll
        for (int j = 0; j < 4; ++j) {
            const unsigned short* ga = eb + (size_t)(mbase + rbase + j*8)*H_ + kc*64 + k8;
            __builtin_amdgcn_global_load_lds(AS_G(ga), AS_L(As + (w*4+j)*512), 16, 0, 0);
            const unsigned short* gw = wb + (size_t)(nbase + rbase + j*8)*H_ + kc*64 + k8;
            __builtin_amdgcn_global_load_lds(AS_G(gw), AS_L(Bs + (w*4+j)*512), 16, 0, 0);
        }
        __syncthreads();
        #pragma unroll
        for (int kk = 0; kk < 2; ++kk) {
            bf16x8 af[4], bfr[4];
            #pragma unroll
            for (int mi=0;mi<4;mi++)
                af[mi] = *(const bf16x8*)(As + (wrow*64 + mi*16 + m)*64 + kk*32 + q*8);
            #pragma unroll
            for (int ni=0;ni<4;ni++)
                bfr[ni] = *(const bf16x8*)(Bs + (wcol*64 + ni*16 + m)*64 + kk*32 + q*8);
            #pragma unroll
            for (int mi=0;mi<4;mi++)
                #pragma unroll
                for (int ni=0;ni<4;ni++)
                    acc[mi][ni] = __builtin_amdgcn_mfma_f32_16x16x32_bf16(
                        af[mi], bfr[ni], acc[mi][ni], 0, 0, 0);
        }
    }

    float bv[4];
    #pragma unroll
    for (int ni=0;ni<4;ni++) bv[ni] = bias[nbase + wcol*64 + ni*16 + m];
    #pragma unroll
    for (int mi=0;mi<4;mi++) {
        #pragma unroll
        for (int r=0;r<4;r++) {
            float s = 0.f;
            #pragma unroll
            for (int ni=0;ni<4;ni++)
                s += exp2f((acc[mi][ni][r] + bv[ni]) * LOG2E - LSE_SHIFT);
            s += __shfl_xor(s, 1);
            s += __shfl_xor(s, 2);
            s += __shfl_xor(s, 4);
            s += __shfl_xor(s, 8);
            if (m == 0) atomicAdd(&rs[wrow*64 + mi*16 + q*4 + r], s);
        }
    }
    __syncthreads();
    if (tid < 128) atomicAdd(&Srow[mbase + tid], rs[tid]);
}

// ---------------------------------------------------------------------------
// Kernel 2: gather ext-label probs via MFMA (B-rows gathered by vocab id).
// ---------------------------------------------------------------------------
__global__ __launch_bounds__(256) void gather_mfma_kernel(
        const unsigned short* __restrict__ eb, const unsigned short* __restrict__ wb,
        const float* __restrict__ bias, const int* __restrict__ ys,
        const float* __restrict__ Srow, float* __restrict__ g)
{
    __shared__ __align__(16) unsigned short As[128*64];
    __shared__ __align__(16) unsigned short Bs[128*64];
    __shared__ float ls[128];
    const int tid  = threadIdx.x;
    const int w    = tid >> 6;
    const int lane = tid & 63;
    const int m    = lane & 15;
    const int q    = lane >> 4;
    const int wrow = w >> 1;
    const int wcol = w & 1;
    const int b    = blockIdx.y;
    const int tb   = blockIdx.x * 128;

    if (tid < 128) {
        int t = tb + tid;
        ls[tid] = (t < T_) ? (LSE_SHIFT + log2f(Srow[b*T_ + t])) : 0.f;
    }

    const int rbase = w*32 + (lane >> 3);
    const int k8    = (lane & 7) * 8;

    int vrow[4];
    #pragma unroll
    for (int j=0;j<4;++j) {
        int labr = rbase + j*8;
        vrow[j] = (labr == 0 || labr > L_) ? 0 : ys[b*L_ + labr - 1];
    }
    int labc[4]; float bv[4];
    #pragma unroll
    for (int ni=0;ni<4;++ni) {
        int lab = wcol*64 + ni*16 + m;
        labc[ni] = lab;
        int v = (lab == 0 || lab > L_) ? 0 : ys[b*L_ + lab - 1];
        bv[ni] = bias[v];
    }

    f32x4 acc[4][4];
    #pragma unroll
    for (int i=0;i<4;i++)
        #pragma unroll
        for (int j=0;j<4;j++) acc[i][j] = (f32x4){0.f,0.f,0.f,0.f};

    for (int kc = 0; kc < 8; ++kc) {
        __syncthreads();
        #pragma unroll
        for (int j = 0; j < 4; ++j) {
            const unsigned short* ga = eb + (size_t)(b*T_ + tb + rbase + j*8)*H_ + kc*64 + k8;
            __builtin_amdgcn_global_load_lds(AS_G(ga), AS_L(As + (w*4+j)*512), 16, 0, 0);
            const unsigned short* gw = wb + (size_t)vrow[j]*H_ + kc*64 + k8;
            __builtin_amdgcn_global_load_lds(AS_G(gw), AS_L(Bs + (w*4+j)*512), 16, 0, 0);
        }
        __syncthreads();
        #pragma unroll
        for (int kk = 0; kk < 2; ++kk) {
            bf16x8 af[4], bfr[4];
            #pragma unroll
            for (int mi=0;mi<4;mi++)
                af[mi] = *(const bf16x8*)(As + (wrow*64 + mi*16 + m)*64 + kk*32 + q*8);
            #pragma unroll
            for (int ni=0;ni<4;ni++)
                bfr[ni] = *(const bf16x8*)(Bs + (wcol*64 + ni*16 + m)*64 + kk*32 + q*8);
            #pragma unroll
            for (int mi=0;mi<4;mi++)
                #pragma unroll
                for (int ni=0;ni<4;ni++)
                    acc[mi][ni] = __builtin_amdgcn_mfma_f32_16x16x32_bf16(
                        af[mi], bfr[ni], acc[mi][ni], 0, 0, 0);
        }
    }

    #pragma unroll
    for (int mi=0;mi<4;mi++) {
        #pragma unroll
        for (int r=0;r<4;r++) {
            int trow = wrow*64 + mi*16 + q*4 + r;
            int t = tb + trow;
            float l2 = ls[trow];
            #pragma unroll
            for (int ni=0;ni<4;ni++) {
                if (t < T_ && labc[ni] <= L_) {
                    float p = exp2f((acc[mi][ni][r] + bv[ni]) * LOG2E - l2);
                    int off = (labc[ni] == 0) ? 0 : labc[ni] + 1;
                    g[(size_t)(b*T_ + t)*GSTRIDE + off] = p;
                }
            }
        }
    }
}

// ---------------------------------------------------------------------------
// Kernel 3: CTC forward DP, linear domain, DPP cross-lane, 24-step chunks
// with 2x-unrolled double-buffer prefetch. One wave per batch element.
// ---------------------------------------------------------------------------
#define CH 24

struct DpState {
    float a0, a1, a2, a3, C2;
    float msk0, msk1, msk2, msk3, sk1, sk3;
};

__device__ __forceinline__ void dp_chunk(DpState& st, int tb, int elen,
                                         const float* pb, const float2* pl)
{
    #pragma unroll
    for (int j = 0; j < CH; ++j) {
        int t = tb + j;
        if (t < elen) {                       // wave-uniform (scalar) guard
            float um1 = dpp_shr1(st.a3);      // prev-lane a3; lane0 -> 0
            float n0 = st.a0 + um1;
            float n1 = st.a1 + st.a0 + st.sk1*um1;
            float n2 = st.a2 + st.a1;
            float n3 = st.a3 + st.a2 + st.sk3*st.a1;
            st.a0 = n0 * pb[j]   * st.msk0;
            st.a1 = n1 * pl[j].x * st.msk1;
            st.a2 = n2 * pb[j]   * st.msk2;
            st.a3 = n3 * pl[j].y * st.msk3;
        }
        if ((j & 3) == 3) {                   // renorm every 4 steps (exact)
            float mm = wave_max_nonneg(fmaxf(fmaxf(st.a0,st.a1), fmaxf(st.a2,st.a3)));
            if (mm > 0.f) {
                float rr = 1.0f / mm;
                st.C2 += __log2f(mm);
                st.a0 *= rr; st.a1 *= rr; st.a2 *= rr; st.a3 *= rr;
            }
        }
    }
}

__global__ __launch_bounds__(64, 1) void ctc_dp_kernel(
        const float* __restrict__ g, const int* __restrict__ ys,
        const int* __restrict__ elens, const int* __restrict__ ylens,
        float* __restrict__ out)
{
    const int b    = blockIdx.x;
    const int lane = threadIdx.x;
    const float* gb = g + (size_t)b * T_ * GSTRIDE;
    const int ylen = ylens[b];
    const int elen = elens[b];
    const int Sv   = 2*ylen + 1;
    const int s0   = 4*lane;

    DpState st;
    st.msk0 = (s0   < Sv) ? 1.f : 0.f;
    st.msk1 = (s0+1 < Sv) ? 1.f : 0.f;
    st.msk2 = (s0+2 < Sv) ? 1.f : 0.f;
    st.msk3 = (s0+3 < Sv) ? 1.f : 0.f;
    const int l0 = 2*lane, l1 = 2*lane + 1;
    int i0 = min(max(l0,1), L_-1);
    int i1 = min(l1, L_-1);
    st.sk1 = (l0 >= 1 && l0 < L_ && ys[b*L_+i0] != ys[b*L_+i0-1]) ? 1.f : 0.f;
    st.sk3 = (l1 < L_        && ys[b*L_+i1] != ys[b*L_+i1-1]) ? 1.f : 0.f;
    const bool ldok = (lane < 51);

    float pb0  = gb[0];
    float2 pl0 = ldok ? *(const float2*)(gb + 2 + 2*lane) : make_float2(0.f,0.f);
    st.a0 = (lane==0) ? pb0   : 0.f;
    st.a1 = (lane==0) ? pl0.x : 0.f;
    st.a2 = 0.f; st.a3 = 0.f; st.C2 = 0.f;

    float pbA[CH], pbB[CH]; float2 plA[CH], plB[CH];
    #pragma unroll
    for (int j=0;j<CH;++j) {                            // preload chunk t=1..CH
        int tt = min(1+j, T_-1);
        pbA[j] = gb[tt*GSTRIDE];
        plA[j] = ldok ? *(const float2*)(gb + tt*GSTRIDE + 2 + 2*lane) : make_float2(0.f,0.f);
    }

    for (int tb = 1; tb < elen; tb += 2*CH) {
        #pragma unroll
        for (int j=0;j<CH;++j) {                        // prefetch chunk tb+CH
            int tt = min(tb+CH+j, T_-1);
            pbB[j] = gb[tt*GSTRIDE];
            plB[j] = ldok ? *(const float2*)(gb + tt*GSTRIDE + 2 + 2*lane) : make_float2(0.f,0.f);
        }
        dp_chunk(st, tb, elen, pbA, plA);
        #pragma unroll
        for (int j=0;j<CH;++j) {                        // prefetch chunk tb+2*CH
            int tt = min(tb+2*CH+j, T_-1);
            pbA[j] = gb[tt*GSTRIDE];
            plA[j] = ldok ? *(const float2*)(gb + tt*GSTRIDE + 2 + 2*lane) : make_float2(0.f,0.f);
        }
        dp_chunk(st, tb+CH, elen, pbB, plB);
    }

    int sA = 2*ylen, sB = sA - 1;
    float vA = __shfl((sA & 2) ? st.a2 : st.a0, sA >> 2);
    float vB = __shfl((sB & 2) ? st.a3 : st.a1, sB >> 2);
    if (lane == 0) {
        float sum = vA + vB;
        float loss = 0.f;
        if (sum > 0.f) {
            loss = -(log2f(sum) + st.C2) * 0.6931471805599453f;
            if (!(loss < 5e9f)) loss = 0.f;             // zero_infinity
        }
        atomicAdd(out, loss * (1.0f/B_));
    }
}

// ---------------------------------------------------------------------------
extern "C" void kernel_launch(void* const* d_in, const int* in_sizes, int n_in,
                              void* d_out, int out_size, void* d_ws, size_t ws_size,
                              hipStream_t stream)
{
    const float* eouts = (const float*)d_in[0];
    const float* W     = (const float*)d_in[1];
    const float* bias  = (const float*)d_in[2];
    const int*   ys    = (const int*)d_in[3];
    const int*   elens = (const int*)d_in[4];
    const int*   ylens = (const int*)d_in[5];
    float* out = (float*)d_out;

    char* ws = (char*)d_ws;
    unsigned short* eb = (unsigned short*)ws;                  // 32,768,000 B
    unsigned short* wb = (unsigned short*)(ws + 32768000);     //  2,097,152 B
    float* Srow        = (float*)(ws + 34865152);              //    128,000 B
    float* g           = (float*)(ws + 34993152);              // 13,313,024 B

    prep_kernel<<<17057, 256, 0, stream>>>(eouts, W, eb, wb, Srow, out);
    gemm_lse_kernel<<<dim3(16, 250), 256, 0, stream>>>(eb, wb, bias, Srow);
    gather_mfma_kernel<<<dim3(8, 32), 256, 0, stream>>>(eb, wb, bias, ys, Srow, g);
    ctc_dp_kernel<<<B_, 64, 0, stream>>>(g, ys, elens, ylens, out);
}

// Round 5
// 387.255 us; speedup vs baseline: 1.2531x; 1.2531x over previous
//
#include <hip/hip_runtime.h>
#include <hip/hip_bf16.h>

#define B_ 32
#define T_ 1000
#define H_ 512
#define V_ 2048
#define L_ 100
#define M_ (B_*T_)          // 32000 rows
#define GSTRIDE 104         // p_ext row stride (floats): [0]=blank, [2+l]=label l
#define LOG2E 1.4426950408889634f
#define LSE_SHIFT 48.0f
#define BIAS60 1.152921504606847e18f   // 2^60

typedef __attribute__((ext_vector_type(8))) short bf16x8;
typedef __attribute__((ext_vector_type(4))) float f32x4;

#define AS_G(p)  ((const __attribute__((address_space(1))) unsigned int*)(p))
#define AS_L(p)  ((__attribute__((address_space(3))) unsigned int*)(p))

// s_waitcnt with only vmcnt constrained (lgkm=15, exp=7 = no wait).
#define WAITVM(N) __builtin_amdgcn_s_waitcnt(((N)&15) | ((((N)>>4)&3)<<14) | (7<<4) | (15<<8))

__device__ __forceinline__ unsigned short f2bf(float x) {
    unsigned int u; __builtin_memcpy(&u, &x, 4);
    unsigned int r = (u + 0x7fffu + ((u >> 16) & 1u)) >> 16;   // RNE
    return (unsigned short)r;
}

// DPP helpers (verified correct in R3: same absmax as shfl version).
__device__ __forceinline__ float dpp_shr1(float x) {          // lane i <- lane i-1, lane0 <- 0
    int r = __builtin_amdgcn_update_dpp(0, __builtin_bit_cast(int, x), 0x138, 0xf, 0xf, false);
    return __builtin_bit_cast(float, r);
}
template<int CTRL>
__device__ __forceinline__ float fmax_dpp(float x) {          // zero-fill ok: operands >= 0
    int s = __builtin_amdgcn_update_dpp(0, __builtin_bit_cast(int, x), CTRL, 0xf, 0xf, false);
    return fmaxf(x, __builtin_bit_cast(float, s));
}
__device__ __forceinline__ float wave_max_nonneg(float x) {   // max over 64 lanes, broadcast
    x = fmax_dpp<0x111>(x);
    x = fmax_dpp<0x112>(x);
    x = fmax_dpp<0x114>(x);
    x = fmax_dpp<0x118>(x);
    x = fmax_dpp<0x142>(x);
    x = fmax_dpp<0x143>(x);
    return __builtin_bit_cast(float, __builtin_amdgcn_readlane(__builtin_bit_cast(int, x), 63));
}

// ---------------------------------------------------------------------------
// Kernel 0: zero out + Srow, convert eouts/W fp32 -> bf16 into ws
// ---------------------------------------------------------------------------
__global__ __launch_bounds__(256) void prep_kernel(
        const float* __restrict__ eouts, const float* __restrict__ W,
        unsigned short* __restrict__ eb, unsigned short* __restrict__ wb,
        float* __restrict__ Srow, float* __restrict__ out)
{
    const int E4 = M_*H_/4;      // 4,096,000
    const int W4 = V_*H_/4;      //   262,144
    const int S4 = M_/4;         //     8,000
    int idx = blockIdx.x*256 + threadIdx.x;
    if (idx == 0) out[0] = 0.f;
    if (idx < E4) {
        float4 v = ((const float4*)eouts)[idx];
        ushort4 o; o.x=f2bf(v.x); o.y=f2bf(v.y); o.z=f2bf(v.z); o.w=f2bf(v.w);
        ((ushort4*)eb)[idx] = o;
    } else if (idx < E4 + W4) {
        int j = idx - E4;
        float4 v = ((const float4*)W)[j];
        ushort4 o; o.x=f2bf(v.x); o.y=f2bf(v.y); o.z=f2bf(v.z); o.w=f2bf(v.w);
        ((ushort4*)wb)[j] = o;
    } else if (idx < E4 + W4 + S4) {
        int j = idx - E4 - W4;
        ((float4*)Srow)[j] = make_float4(0.f,0.f,0.f,0.f);
    }
}

// ---------------------------------------------------------------------------
// Kernel 1: m97-style bf16 MFMA GEMM (logits = eouts @ W^T + b) fused with
// row-wise sum of 2^(z*log2e - 48). 128x128 tile, BK=64, global_load_lds x16.
// ---------------------------------------------------------------------------
__global__ __launch_bounds__(256) void gemm_lse_kernel(
        const unsigned short* __restrict__ eb, const unsigned short* __restrict__ wb,
        const float* __restrict__ bias, float* __restrict__ Srow)
{
    __shared__ __align__(16) unsigned short As[128*64];
    __shared__ __align__(16) unsigned short Bs[128*64];
    __shared__ float rs[128];
    const int tid  = threadIdx.x;
    const int w    = tid >> 6;
    const int lane = tid & 63;
    const int m    = lane & 15;
    const int q    = lane >> 4;
    const int wrow = w >> 1;
    const int wcol = w & 1;
    const int nbase = blockIdx.x * 128;
    const int mbase = blockIdx.y * 128;
    if (tid < 128) rs[tid] = 0.f;

    const int rbase = w*32 + (lane >> 3);
    const int k8    = (lane & 7) * 8;

    f32x4 acc[4][4];
    #pragma unroll
    for (int i=0;i<4;i++)
        #pragma unroll
        for (int j=0;j<4;j++) acc[i][j] = (f32x4){0.f,0.f,0.f,0.f};

    for (int kc = 0; kc < 8; ++kc) {
        __syncthreads();
        #pragma unroll
        for (int j = 0; j < 4; ++j) {
            const unsigned short* ga = eb + (size_t)(mbase + rbase + j*8)*H_ + kc*64 + k8;
            __builtin_amdgcn_global_load_lds(AS_G(ga), AS_L(As + (w*4+j)*512), 16, 0, 0);
            const unsigned short* gw = wb + (size_t)(nbase + rbase + j*8)*H_ + kc*64 + k8;
            __builtin_amdgcn_global_load_lds(AS_G(gw), AS_L(Bs + (w*4+j)*512), 16, 0, 0);
        }
        __syncthreads();
        #pragma unroll
        for (int kk = 0; kk < 2; ++kk) {
            bf16x8 af[4], bfr[4];
            #pragma unroll
            for (int mi=0;mi<4;mi++)
                af[mi] = *(const bf16x8*)(As + (wrow*64 + mi*16 + m)*64 + kk*32 + q*8);
            #pragma unroll
            for (int ni=0;ni<4;ni++)
                bfr[ni] = *(const bf16x8*)(Bs + (wcol*64 + ni*16 + m)*64 + kk*32 + q*8);
            #pragma unroll
            for (int mi=0;mi<4;mi++)
                #pragma unroll
                for (int ni=0;ni<4;ni++)
                    acc[mi][ni] = __builtin_amdgcn_mfma_f32_16x16x32_bf16(
                        af[mi], bfr[ni], acc[mi][ni], 0, 0, 0);
        }
    }

    float bv[4];
    #pragma unroll
    for (int ni=0;ni<4;ni++) bv[ni] = bias[nbase + wcol*64 + ni*16 + m];
    #pragma unroll
    for (int mi=0;mi<4;mi++) {
        #pragma unroll
        for (int r=0;r<4;r++) {
            float s = 0.f;
            #pragma unroll
            for (int ni=0;ni<4;ni++)
                s += exp2f((acc[mi][ni][r] + bv[ni]) * LOG2E - LSE_SHIFT);
            s += __shfl_xor(s, 1);
            s += __shfl_xor(s, 2);
            s += __shfl_xor(s, 4);
            s += __shfl_xor(s, 8);
            if (m == 0) atomicAdd(&rs[wrow*64 + mi*16 + q*4 + r], s);
        }
    }
    __syncthreads();
    if (tid < 128) atomicAdd(&Srow[mbase + tid], rs[tid]);
}

// ---------------------------------------------------------------------------
// Kernel 2: gather ext-label probs via MFMA (B-rows gathered by vocab id).
// ---------------------------------------------------------------------------
__global__ __launch_bounds__(256) void gather_mfma_kernel(
        const unsigned short* __restrict__ eb, const unsigned short* __restrict__ wb,
        const float* __restrict__ bias, const int* __restrict__ ys,
        const float* __restrict__ Srow, float* __restrict__ g)
{
    __shared__ __align__(16) unsigned short As[128*64];
    __shared__ __align__(16) unsigned short Bs[128*64];
    __shared__ float ls[128];
    const int tid  = threadIdx.x;
    const int w    = tid >> 6;
    const int lane = tid & 63;
    const int m    = lane & 15;
    const int q    = lane >> 4;
    const int wrow = w >> 1;
    const int wcol = w & 1;
    const int b    = blockIdx.y;
    const int tb   = blockIdx.x * 128;

    if (tid < 128) {
        int t = tb + tid;
        ls[tid] = (t < T_) ? (LSE_SHIFT + log2f(Srow[b*T_ + t])) : 0.f;
    }

    const int rbase = w*32 + (lane >> 3);
    const int k8    = (lane & 7) * 8;

    int vrow[4];
    #pragma unroll
    for (int j=0;j<4;++j) {
        int labr = rbase + j*8;
        vrow[j] = (labr == 0 || labr > L_) ? 0 : ys[b*L_ + labr - 1];
    }
    int labc[4]; float bv[4];
    #pragma unroll
    for (int ni=0;ni<4;++ni) {
        int lab = wcol*64 + ni*16 + m;
        labc[ni] = lab;
        int v = (lab == 0 || lab > L_) ? 0 : ys[b*L_ + lab - 1];
        bv[ni] = bias[v];
    }

    f32x4 acc[4][4];
    #pragma unroll
    for (int i=0;i<4;i++)
        #pragma unroll
        for (int j=0;j<4;j++) acc[i][j] = (f32x4){0.f,0.f,0.f,0.f};

    for (int kc = 0; kc < 8; ++kc) {
        __syncthreads();
        #pragma unroll
        for (int j = 0; j < 4; ++j) {
            const unsigned short* ga = eb + (size_t)(b*T_ + tb + rbase + j*8)*H_ + kc*64 + k8;
            __builtin_amdgcn_global_load_lds(AS_G(ga), AS_L(As + (w*4+j)*512), 16, 0, 0);
            const unsigned short* gw = wb + (size_t)vrow[j]*H_ + kc*64 + k8;
            __builtin_amdgcn_global_load_lds(AS_G(gw), AS_L(Bs + (w*4+j)*512), 16, 0, 0);
        }
        __syncthreads();
        #pragma unroll
        for (int kk = 0; kk < 2; ++kk) {
            bf16x8 af[4], bfr[4];
            #pragma unroll
            for (int mi=0;mi<4;mi++)
                af[mi] = *(const bf16x8*)(As + (wrow*64 + mi*16 + m)*64 + kk*32 + q*8);
            #pragma unroll
            for (int ni=0;ni<4;ni++)
                bfr[ni] = *(const bf16x8*)(Bs + (wcol*64 + ni*16 + m)*64 + kk*32 + q*8);
            #pragma unroll
            for (int mi=0;mi<4;mi++)
                #pragma unroll
                for (int ni=0;ni<4;ni++)
                    acc[mi][ni] = __builtin_amdgcn_mfma_f32_16x16x32_bf16(
                        af[mi], bfr[ni], acc[mi][ni], 0, 0, 0);
        }
    }

    #pragma unroll
    for (int mi=0;mi<4;mi++) {
        #pragma unroll
        for (int r=0;r<4;r++) {
            int trow = wrow*64 + mi*16 + q*4 + r;
            int t = tb + trow;
            float l2 = ls[trow];
            #pragma unroll
            for (int ni=0;ni<4;ni++) {
                if (t < T_ && labc[ni] <= L_) {
                    float p = exp2f((acc[mi][ni][r] + bv[ni]) * LOG2E - l2);
                    int off = (labc[ni] == 0) ? 0 : labc[ni] + 1;
                    g[(size_t)(b*T_ + t)*GSTRIDE + off] = p;
                }
            }
        }
    }
}

// ---------------------------------------------------------------------------
// Kernel 3: CTC forward DP. One wave per b. Rows stream through a 32-slot
// x 1024 B LDS ring via global_load_lds (PER-LANE global addr + lane*16 LDS
// scatter — R4 bug was a uniform global addr). Manual vmcnt pipeline; stale
// wave-max boost renorm off the critical path, exactly accounted in C2.
// ---------------------------------------------------------------------------
#define NV 12            // DMA depth in chunks (2 pair-loads per chunk)
#define KW 21            // vmcnt target: 2*NV-3
#define SROW_MAX (T_-4)  // clamp DMA start row so the 1 KB slot stays in g[b]

__global__ __launch_bounds__(64, 1) void ctc_dp_kernel(
        const float* __restrict__ g, const int* __restrict__ ys,
        const int* __restrict__ elens, const int* __restrict__ ylens,
        float* __restrict__ out)
{
    __shared__ __align__(16) float ring[32*256];   // 32 pair-slots x 1024 B
    const int b    = blockIdx.x;
    const int lane = threadIdx.x;
    const float* gb = g + (size_t)b * T_ * GSTRIDE;
    const int ylen = ylens[b];
    const int elen = elens[b];
    const int Sv   = 2*ylen + 1;
    const int s0   = 4*lane;
    const float msk0 = (s0   < Sv) ? 1.f : 0.f;
    const float msk1 = (s0+1 < Sv) ? 1.f : 0.f;
    const float msk2 = (s0+2 < Sv) ? 1.f : 0.f;
    const float msk3 = (s0+3 < Sv) ? 1.f : 0.f;
    const int l0 = 2*lane, l1 = 2*lane + 1;
    int i0 = min(max(l0,1), L_-1);
    int i1 = min(l1, L_-1);
    const float sk1 = (l0 >= 1 && l0 < L_ && ys[b*L_+i0] != ys[b*L_+i0-1]) ? 1.f : 0.f;
    const float sk3 = (l1 < L_        && ys[b*L_+i1] != ys[b*L_+i1-1]) ? 1.f : 0.f;
    const bool ldok = (lane < 51);

    float a0, a1, a2, a3, C2 = 0.f, rr = 1.f, l2rr = 0.f;

    // warm-up DMA: pairs 0..2*NV-1 (rows 0..4*NV-1). Per-lane global address!
    #pragma unroll
    for (int pr = 0; pr < 2*NV; ++pr) {
        int srow = min(2*pr, SROW_MAX);
        __builtin_amdgcn_global_load_lds(AS_G(gb + (size_t)srow*GSTRIDE + 4*lane),
                                         AS_L(ring + (pr & 31)*256), 16, 0, 0);
    }

    // init alphas (t=0) straight from global
    a0 = (lane == 0) ? gb[0] : 0.f;
    a1 = (lane == 0) ? gb[2] : 0.f;
    a2 = 0.f; a3 = 0.f;

    auto dpstep = [&](float p0, float p1, float p2, float p3) {
        float um1 = dpp_shr1(a3);
        float n0 = a0 + um1;
        float n1 = a1 + a0 + sk1*um1;
        float n2 = a2 + a1;
        float n3 = a3 + a2 + sk3*a1;
        a0 = n0*p0; a1 = n1*p1; a2 = n2*p2; a3 = n3*p3;
    };

    float Pa[16], Pb[16];

    WAITVM(KW);   // pairs 0..2 landed -> chunk 0 rows (t=1..4) readable
    #pragma unroll
    for (int j = 0; j < 4; ++j) {      // preload chunk 0 -> Pa
        int t = 1 + j;
        const float* base = ring + ((t >> 1) & 31)*256 + (t & 1)*GSTRIDE;
        float pb = base[0];
        float2 pl = *(const float2*)(base + 2 + 2*lane);
        Pa[4*j+0] = pb*msk0; Pa[4*j+1] = pl.x*msk1;
        Pa[4*j+2] = pb*msk2; Pa[4*j+3] = pl.y*msk3;
    }

    auto body = [&](float (&Pin)[16], float (&Pout)[16], int c) {
        // 1. apply stale boost (exactly accounted)
        a0 *= rr; a1 *= rr; a2 *= rr; a3 *= rr; C2 -= l2rr;
        // 2. next boost from post-boost alphas (latency overlaps DP below)
        float mm = wave_max_nonneg(fmaxf(fmaxf(a0,a1), fmaxf(a2,a3)));
        float rrn = 1.f, l2n = 0.f;
        if (mm > 0.f) { rrn = __fdividef(BIAS60, mm); l2n = __log2f(rrn); }
        // 3. DMA pairs for rows 4*(NV+c)..+3 (per-lane global address)
        #pragma unroll
        for (int u = 0; u < 2; ++u) {
            int pr = 2*(NV + c) + u;
            int srow = min(2*pr, SROW_MAX);
            __builtin_amdgcn_global_load_lds(AS_G(gb + (size_t)srow*GSTRIDE + 4*lane),
                                             AS_L(ring + (pr & 31)*256), 16, 0, 0);
        }
        // 4. ensure chunk c+1 rows landed (issued 24+2c+2, wait 21 -> 2c+5 pairs)
        WAITVM(KW);
        // 5. stage chunk c+1 -> Pout (independent of DP chain)
        #pragma unroll
        for (int j = 0; j < 4; ++j) {
            int t = 4*c + 5 + j;
            const float* base = ring + ((t >> 1) & 31)*256 + (t & 1)*GSTRIDE;
            float pb = base[0];
            float2 pl = *(const float2*)(base + 2 + 2*lane);
            Pout[4*j+0] = pb*msk0; Pout[4*j+1] = pl.x*msk1;
            Pout[4*j+2] = pb*msk2; Pout[4*j+3] = pl.y*msk3;
        }
        // 6. DP chunk c (critical chain)
        #pragma unroll
        for (int j = 0; j < 4; ++j)
            dpstep(Pin[4*j], Pin[4*j+1], Pin[4*j+2], Pin[4*j+3]);
        rr = rrn; l2rr = l2n;
    };

    const int F  = (elen - 5)/4 + 1;   // 4*F <= elen-1 (elen >= 201)
    const int F2 = F & ~1;
    for (int c = 0; c < F2; c += 2) {
        body(Pa, Pb, c);
        body(Pb, Pa, c+1);
    }

    // tail: up to 7 steps, straight from global (latency irrelevant)
    for (int t = 4*F2 + 1; t < elen; ++t) {
        const float* base = gb + (size_t)t*GSTRIDE;
        float pb = base[0];
        float2 pl = ldok ? *(const float2*)(base + 2 + 2*lane) : make_float2(0.f,0.f);
        dpstep(pb*msk0, pl.x*msk1, pb*msk2, pl.y*msk3);
        float mm = wave_max_nonneg(fmaxf(fmaxf(a0,a1), fmaxf(a2,a3)));
        if (mm > 0.f) {
            float r = __fdividef(1.f, mm);
            C2 += __log2f(mm);
            a0 *= r; a1 *= r; a2 *= r; a3 *= r;
        }
    }

    int sA = 2*ylen, sB = sA - 1;
    float vA = __shfl((sA & 2) ? a2 : a0, sA >> 2);
    float vB = __shfl((sB & 2) ? a3 : a1, sB >> 2);
    if (lane == 0) {
        float sum = vA + vB;
        float loss = 0.f;
        if (sum > 0.f) {
            loss = -(log2f(sum) + C2) * 0.6931471805599453f;
            if (!(loss < 5e9f)) loss = 0.f;             // zero_infinity
        }
        atomicAdd(out, loss * (1.0f/B_));
    }
}

// ---------------------------------------------------------------------------
extern "C" void kernel_launch(void* const* d_in, const int* in_sizes, int n_in,
                              void* d_out, int out_size, void* d_ws, size_t ws_size,
                              hipStream_t stream)
{
    const float* eouts = (const float*)d_in[0];
    const float* W     = (const float*)d_in[1];
    const float* bias  = (const float*)d_in[2];
    const int*   ys    = (const int*)d_in[3];
    const int*   elens = (const int*)d_in[4];
    const int*   ylens = (const int*)d_in[5];
    float* out = (float*)d_out;

    char* ws = (char*)d_ws;
    unsigned short* eb = (unsigned short*)ws;                  // 32,768,000 B
    unsigned short* wb = (unsigned short*)(ws + 32768000);     //  2,097,152 B
    float* Srow        = (float*)(ws + 34865152);              //    128,000 B
    float* g           = (float*)(ws + 34993152);              // 13,312,000 B

    prep_kernel<<<17057, 256, 0, stream>>>(eouts, W, eb, wb, Srow, out);
    gemm_lse_kernel<<<dim3(16, 250), 256, 0, stream>>>(eb, wb, bias, Srow);
    gather_mfma_kernel<<<dim3(8, 32), 256, 0, stream>>>(eb, wb, bias, ys, Srow, g);
    ctc_dp_kernel<<<B_, 64, 0, stream>>>(g, ys, elens, ylens, out);
}

// Round 9
// 370.004 us; speedup vs baseline: 1.3116x; 1.0466x over previous
//
#include <hip/hip_runtime.h>
#include <hip/hip_bf16.h>

#define B_ 32
#define T_ 1000
#define H_ 512
#define V_ 2048
#define L_ 100
#define M_ (B_*T_)          // 32000 rows
#define GSTRIDE 104         // p_ext row stride (floats): [0]=blank, [2+l]=label l
#define LOG2E 1.4426950408889634f
#define LSE_SHIFT 48.0f
#define BIAS60 1.152921504606847e18f   // 2^60

typedef __attribute__((ext_vector_type(8))) short bf16x8;
typedef __attribute__((ext_vector_type(4))) float f32x4;

#define AS_G(p)  ((const __attribute__((address_space(1))) unsigned int*)(p))
#define AS_L(p)  ((__attribute__((address_space(3))) unsigned int*)(p))

// s_waitcnt with only vmcnt constrained (lgkm=15, exp=7 = no wait).
#define WAITVM(N) __builtin_amdgcn_s_waitcnt(((N)&15) | ((((N)>>4)&3)<<14) | (7<<4) | (15<<8))

__device__ __forceinline__ unsigned short f2bf(float x) {
    unsigned int u; __builtin_memcpy(&u, &x, 4);
    unsigned int r = (u + 0x7fffu + ((u >> 16) & 1u)) >> 16;   // RNE
    return (unsigned short)r;
}

// DPP helpers (verified R3/R5).
__device__ __forceinline__ float dpp_shr1(float x) {          // lane i <- lane i-1, lane0 <- 0
    int r = __builtin_amdgcn_update_dpp(0, __builtin_bit_cast(int, x), 0x138, 0xf, 0xf, false);
    return __builtin_bit_cast(float, r);
}
template<int CTRL>
__device__ __forceinline__ float fmax_dpp(float x) {          // zero-fill ok: operands >= 0
    int s = __builtin_amdgcn_update_dpp(0, __builtin_bit_cast(int, x), CTRL, 0xf, 0xf, false);
    return fmaxf(x, __builtin_bit_cast(float, s));
}
__device__ __forceinline__ float wave_max_nonneg(float x) {   // max over 64 lanes, broadcast
    x = fmax_dpp<0x111>(x);
    x = fmax_dpp<0x112>(x);
    x = fmax_dpp<0x114>(x);
    x = fmax_dpp<0x118>(x);
    x = fmax_dpp<0x142>(x);
    x = fmax_dpp<0x143>(x);
    return __builtin_bit_cast(float, __builtin_amdgcn_readlane(__builtin_bit_cast(int, x), 63));
}

// ---------------------------------------------------------------------------
// Kernel 0: zero out + Srow, convert eouts/W fp32 -> bf16 into ws
// ---------------------------------------------------------------------------
__global__ __launch_bounds__(256) void prep_kernel(
        const float* __restrict__ eouts, const float* __restrict__ W,
        unsigned short* __restrict__ eb, unsigned short* __restrict__ wb,
        float* __restrict__ Srow, float* __restrict__ out)
{
    const int E4 = M_*H_/4;      // 4,096,000
    const int W4 = V_*H_/4;      //   262,144
    const int S4 = M_/4;         //     8,000
    int idx = blockIdx.x*256 + threadIdx.x;
    if (idx == 0) out[0] = 0.f;
    if (idx < E4) {
        float4 v = ((const float4*)eouts)[idx];
        ushort4 o; o.x=f2bf(v.x); o.y=f2bf(v.y); o.z=f2bf(v.z); o.w=f2bf(v.w);
        ((ushort4*)eb)[idx] = o;
    } else if (idx < E4 + W4) {
        int j = idx - E4;
        float4 v = ((const float4*)W)[j];
        ushort4 o; o.x=f2bf(v.x); o.y=f2bf(v.y); o.z=f2bf(v.z); o.w=f2bf(v.w);
        ((ushort4*)wb)[j] = o;
    } else if (idx < E4 + W4 + S4) {
        int j = idx - E4 - W4;
        ((float4*)Srow)[j] = make_float4(0.f,0.f,0.f,0.f);
    }
}

// ---------------------------------------------------------------------------
// Kernel 1: bf16 MFMA GEMM + fused row-sum of 2^(z*log2e - 48).
// 128x128 tile, BK=64, global_load_lds x16, XOR bank swizzle:
// chunk c of tile-row R lives at R*64 + (c^(R&7))*8 (shorts).
// Staged by permuting the per-lane global chunk: k8 = ((lane&7)^(lane>>3))*8.
// ---------------------------------------------------------------------------
__global__ __launch_bounds__(256) void gemm_lse_kernel(
        const unsigned short* __restrict__ eb, const unsigned short* __restrict__ wb,
        const float* __restrict__ bias, float* __restrict__ Srow)
{
    __shared__ __align__(16) unsigned short As[128*64];
    __shared__ __align__(16) unsigned short Bs[128*64];
    __shared__ float rs[128];
    const int tid  = threadIdx.x;
    const int w    = tid >> 6;
    const int lane = tid & 63;
    const int m    = lane & 15;
    const int q    = lane >> 4;
    const int wrow = w >> 1;
    const int wcol = w & 1;
    const int nbase = blockIdx.x * 128;
    const int mbase = blockIdx.y * 128;
    if (tid < 128) rs[tid] = 0.f;

    const int rbase = w*32 + (lane >> 3);
    const int k8    = (((lane & 7) ^ ((lane >> 3) & 7)) * 8);   // swizzled chunk
    const int rl    = m & 7;                                    // row&7 for frags

    f32x4 acc[4][4];
    #pragma unroll
    for (int i=0;i<4;i++)
        #pragma unroll
        for (int j=0;j<4;j++) acc[i][j] = (f32x4){0.f,0.f,0.f,0.f};

    for (int kc = 0; kc < 8; ++kc) {
        __syncthreads();
        #pragma unroll
        for (int j = 0; j < 4; ++j) {
            const unsigned short* ga = eb + (size_t)(mbase + rbase + j*8)*H_ + kc*64 + k8;
            __builtin_amdgcn_global_load_lds(AS_G(ga), AS_L(As + (w*4+j)*512), 16, 0, 0);
            const unsigned short* gw = wb + (size_t)(nbase + rbase + j*8)*H_ + kc*64 + k8;
            __builtin_amdgcn_global_load_lds(AS_G(gw), AS_L(Bs + (w*4+j)*512), 16, 0, 0);
        }
        __syncthreads();
        #pragma unroll
        for (int kk = 0; kk < 2; ++kk) {
            const int sw = ((kk*4 + q) ^ rl) * 8;
            bf16x8 af[4], bfr[4];
            #pragma unroll
            for (int mi=0;mi<4;mi++)
                af[mi] = *(const bf16x8*)(As + (wrow*8 + mi*2 + (m>>3))*512 + rl*64 + sw);
            #pragma unroll
            for (int ni=0;ni<4;ni++)
                bfr[ni] = *(const bf16x8*)(Bs + (wcol*8 + ni*2 + (m>>3))*512 + rl*64 + sw);
            #pragma unroll
            for (int mi=0;mi<4;mi++)
                #pragma unroll
                for (int ni=0;ni<4;ni++)
                    acc[mi][ni] = __builtin_amdgcn_mfma_f32_16x16x32_bf16(
                        af[mi], bfr[ni], acc[mi][ni], 0, 0, 0);
        }
    }

    float bv[4];
    #pragma unroll
    for (int ni=0;ni<4;ni++) bv[ni] = bias[nbase + wcol*64 + ni*16 + m];
    #pragma unroll
    for (int mi=0;mi<4;mi++) {
        #pragma unroll
        for (int r=0;r<4;r++) {
            float s = 0.f;
            #pragma unroll
            for (int ni=0;ni<4;ni++)
                s += exp2f((acc[mi][ni][r] + bv[ni]) * LOG2E - LSE_SHIFT);
            s += __shfl_xor(s, 1);
            s += __shfl_xor(s, 2);
            s += __shfl_xor(s, 4);
            s += __shfl_xor(s, 8);
            if (m == 0) atomicAdd(&rs[wrow*64 + mi*16 + q*4 + r], s);
        }
    }
    __syncthreads();
    if (tid < 128) atomicAdd(&Srow[mbase + tid], rs[tid]);
}

// ---------------------------------------------------------------------------
// Kernel 2: gather ext-label probs via MFMA (B-rows gathered by vocab id),
// same XOR bank swizzle as kernel 1.
// ---------------------------------------------------------------------------
__global__ __launch_bounds__(256) void gather_mfma_kernel(
        const unsigned short* __restrict__ eb, const unsigned short* __restrict__ wb,
        const float* __restrict__ bias, const int* __restrict__ ys,
        const float* __restrict__ Srow, float* __restrict__ g)
{
    __shared__ __align__(16) unsigned short As[128*64];
    __shared__ __align__(16) unsigned short Bs[128*64];
    __shared__ float ls[128];
    const int tid  = threadIdx.x;
    const int w    = tid >> 6;
    const int lane = tid & 63;
    const int m    = lane & 15;
    const int q    = lane >> 4;
    const int wrow = w >> 1;
    const int wcol = w & 1;
    const int b    = blockIdx.y;
    const int tb   = blockIdx.x * 128;

    if (tid < 128) {
        int t = tb + tid;
        ls[tid] = (t < T_) ? (LSE_SHIFT + log2f(Srow[b*T_ + t])) : 0.f;
    }

    const int rbase = w*32 + (lane >> 3);
    const int k8    = (((lane & 7) ^ ((lane >> 3) & 7)) * 8);
    const int rl    = m & 7;

    int vrow[4];
    #pragma unroll
    for (int j=0;j<4;++j) {
        int labr = rbase + j*8;
        vrow[j] = (labr == 0 || labr > L_) ? 0 : ys[b*L_ + labr - 1];
    }
    int labc[4]; float bv[4];
    #pragma unroll
    for (int ni=0;ni<4;++ni) {
        int lab = wcol*64 + ni*16 + m;
        labc[ni] = lab;
        int v = (lab == 0 || lab > L_) ? 0 : ys[b*L_ + lab - 1];
        bv[ni] = bias[v];
    }

    f32x4 acc[4][4];
    #pragma unroll
    for (int i=0;i<4;i++)
        #pragma unroll
        for (int j=0;j<4;j++) acc[i][j] = (f32x4){0.f,0.f,0.f,0.f};

    for (int kc = 0; kc < 8; ++kc) {
        __syncthreads();
        #pragma unroll
        for (int j = 0; j < 4; ++j) {
            const unsigned short* ga = eb + (size_t)(b*T_ + tb + rbase + j*8)*H_ + kc*64 + k8;
            __builtin_amdgcn_global_load_lds(AS_G(ga), AS_L(As + (w*4+j)*512), 16, 0, 0);
            const unsigned short* gw = wb + (size_t)vrow[j]*H_ + kc*64 + k8;
            __builtin_amdgcn_global_load_lds(AS_G(gw), AS_L(Bs + (w*4+j)*512), 16, 0, 0);
        }
        __syncthreads();
        #pragma unroll
        for (int kk = 0; kk < 2; ++kk) {
            const int sw = ((kk*4 + q) ^ rl) * 8;
            bf16x8 af[4], bfr[4];
            #pragma unroll
            for (int mi=0;mi<4;mi++)
                af[mi] = *(const bf16x8*)(As + (wrow*8 + mi*2 + (m>>3))*512 + rl*64 + sw);
            #pragma unroll
            for (int ni=0;ni<4;ni++)
                bfr[ni] = *(const bf16x8*)(Bs + (wcol*8 + ni*2 + (m>>3))*512 + rl*64 + sw);
            #pragma unroll
            for (int mi=0;mi<4;mi++)
                #pragma unroll
                for (int ni=0;ni<4;ni++)
                    acc[mi][ni] = __builtin_amdgcn_mfma_f32_16x16x32_bf16(
                        af[mi], bfr[ni], acc[mi][ni], 0, 0, 0);
        }
    }

    #pragma unroll
    for (int mi=0;mi<4;mi++) {
        #pragma unroll
        for (int r=0;r<4;r++) {
            int trow = wrow*64 + mi*16 + q*4 + r;
            int t = tb + trow;
            float l2 = ls[trow];
            #pragma unroll
            for (int ni=0;ni<4;ni++) {
                if (t < T_ && labc[ni] <= L_) {
                    float p = exp2f((acc[mi][ni][r] + bv[ni]) * LOG2E - l2);
                    int off = (labc[ni] == 0) ? 0 : labc[ni] + 1;
                    g[(size_t)(b*T_ + t)*GSTRIDE + off] = p;
                }
            }
        }
    }
}

// ---------------------------------------------------------------------------
// Kernel 3: CTC forward DP — R5 version VERBATIM (passed with absmax 0.0).
// 32-slot x 1KB LDS ring via per-lane global_load_lds, WAITVM(21) pipeline,
// stale-by-one-chunk wave-max boost (exactly accounted), masks at staging,
// tail straight from global. DMA start rows clamped to T_-4 (in-bounds).
// ---------------------------------------------------------------------------
#define NV 12            // DMA depth in chunks (2 pair-loads per chunk)
#define KW 21            // vmcnt target: 2*NV-3
#define SROW_MAX (T_-4)  // clamp DMA start row so the 1 KB slot stays in g[b]

__global__ __launch_bounds__(64, 1) void ctc_dp_kernel(
        const float* __restrict__ g, const int* __restrict__ ys,
        const int* __restrict__ elens, const int* __restrict__ ylens,
        float* __restrict__ out)
{
    __shared__ __align__(16) float ring[32*256];   // 32 pair-slots x 1024 B
    const int b    = blockIdx.x;
    const int lane = threadIdx.x;
    const float* gb = g + (size_t)b * T_ * GSTRIDE;
    const int ylen = ylens[b];
    const int elen = elens[b];
    const int Sv   = 2*ylen + 1;
    const int s0   = 4*lane;
    const float msk0 = (s0   < Sv) ? 1.f : 0.f;
    const float msk1 = (s0+1 < Sv) ? 1.f : 0.f;
    const float msk2 = (s0+2 < Sv) ? 1.f : 0.f;
    const float msk3 = (s0+3 < Sv) ? 1.f : 0.f;
    const int l0 = 2*lane, l1 = 2*lane + 1;
    int i0 = min(max(l0,1), L_-1);
    int i1 = min(l1, L_-1);
    const float sk1 = (l0 >= 1 && l0 < L_ && ys[b*L_+i0] != ys[b*L_+i0-1]) ? 1.f : 0.f;
    const float sk3 = (l1 < L_        && ys[b*L_+i1] != ys[b*L_+i1-1]) ? 1.f : 0.f;
    const bool ldok = (lane < 51);

    float a0, a1, a2, a3, C2 = 0.f, rr = 1.f, l2rr = 0.f;

    // warm-up DMA: pairs 0..2*NV-1 (rows 0..4*NV-1). Per-lane global address!
    #pragma unroll
    for (int pr = 0; pr < 2*NV; ++pr) {
        int srow = min(2*pr, SROW_MAX);
        __builtin_amdgcn_global_load_lds(AS_G(gb + (size_t)srow*GSTRIDE + 4*lane),
                                         AS_L(ring + (pr & 31)*256), 16, 0, 0);
    }

    // init alphas (t=0) straight from global
    a0 = (lane == 0) ? gb[0] : 0.f;
    a1 = (lane == 0) ? gb[2] : 0.f;
    a2 = 0.f; a3 = 0.f;

    auto dpstep = [&](float p0, float p1, float p2, float p3) {
        float um1 = dpp_shr1(a3);
        float n0 = a0 + um1;
        float n1 = a1 + a0 + sk1*um1;
        float n2 = a2 + a1;
        float n3 = a3 + a2 + sk3*a1;
        a0 = n0*p0; a1 = n1*p1; a2 = n2*p2; a3 = n3*p3;
    };

    float Pa[16], Pb[16];

    WAITVM(KW);   // pairs 0..2 landed -> chunk 0 rows (t=1..4) readable
    #pragma unroll
    for (int j = 0; j < 4; ++j) {      // preload chunk 0 -> Pa
        int t = 1 + j;
        const float* base = ring + ((t >> 1) & 31)*256 + (t & 1)*GSTRIDE;
        float pb = base[0];
        float2 pl = *(const float2*)(base + 2 + 2*lane);
        Pa[4*j+0] = pb*msk0; Pa[4*j+1] = pl.x*msk1;
        Pa[4*j+2] = pb*msk2; Pa[4*j+3] = pl.y*msk3;
    }

    auto body = [&](float (&Pin)[16], float (&Pout)[16], int c) {
        // 1. apply stale boost (exactly accounted)
        a0 *= rr; a1 *= rr; a2 *= rr; a3 *= rr; C2 -= l2rr;
        // 2. next boost from post-boost alphas (latency overlaps DP below)
        float mm = wave_max_nonneg(fmaxf(fmaxf(a0,a1), fmaxf(a2,a3)));
        float rrn = 1.f, l2n = 0.f;
        if (mm > 0.f) { rrn = __fdividef(BIAS60, mm); l2n = __log2f(rrn); }
        // 3. DMA pairs for rows 4*(NV+c)..+3 (per-lane global address)
        #pragma unroll
        for (int u = 0; u < 2; ++u) {
            int pr = 2*(NV + c) + u;
            int srow = min(2*pr, SROW_MAX);
            __builtin_amdgcn_global_load_lds(AS_G(gb + (size_t)srow*GSTRIDE + 4*lane),
                                             AS_L(ring + (pr & 31)*256), 16, 0, 0);
        }
        // 4. ensure chunk c+1 rows landed (issued 24+2c+2, wait 21 -> 2c+5 pairs)
        WAITVM(KW);
        // 5. stage chunk c+1 -> Pout (independent of DP chain)
        #pragma unroll
        for (int j = 0; j < 4; ++j) {
            int t = 4*c + 5 + j;
            const float* base = ring + ((t >> 1) & 31)*256 + (t & 1)*GSTRIDE;
            float pb = base[0];
            float2 pl = *(const float2*)(base + 2 + 2*lane);
            Pout[4*j+0] = pb*msk0; Pout[4*j+1] = pl.x*msk1;
            Pout[4*j+2] = pb*msk2; Pout[4*j+3] = pl.y*msk3;
        }
        // 6. DP chunk c (critical chain)
        #pragma unroll
        for (int j = 0; j < 4; ++j)
            dpstep(Pin[4*j], Pin[4*j+1], Pin[4*j+2], Pin[4*j+3]);
        rr = rrn; l2rr = l2n;
    };

    const int F  = (elen - 5)/4 + 1;   // 4*F <= elen-1 (elen >= 201)
    const int F2 = F & ~1;
    for (int c = 0; c < F2; c += 2) {
        body(Pa, Pb, c);
        body(Pb, Pa, c+1);
    }

    // tail: up to 7 steps, straight from global (latency irrelevant)
    for (int t = 4*F2 + 1; t < elen; ++t) {
        const float* base = gb + (size_t)t*GSTRIDE;
        float pb = base[0];
        float2 pl = ldok ? *(const float2*)(base + 2 + 2*lane) : make_float2(0.f,0.f);
        dpstep(pb*msk0, pl.x*msk1, pb*msk2, pl.y*msk3);
        float mm = wave_max_nonneg(fmaxf(fmaxf(a0,a1), fmaxf(a2,a3)));
        if (mm > 0.f) {
            float r = __fdividef(1.f, mm);
            C2 += __log2f(mm);
            a0 *= r; a1 *= r; a2 *= r; a3 *= r;
        }
    }

    int sA = 2*ylen, sB = sA - 1;
    float vA = __shfl((sA & 2) ? a2 : a0, sA >> 2);
    float vB = __shfl((sB & 2) ? a3 : a1, sB >> 2);
    if (lane == 0) {
        float sum = vA + vB;
        float loss = 0.f;
        if (sum > 0.f) {
            loss = -(log2f(sum) + C2) * 0.6931471805599453f;
            if (!(loss < 5e9f)) loss = 0.f;             // zero_infinity
        }
        atomicAdd(out, loss * (1.0f/B_));
    }
}

// ---------------------------------------------------------------------------
extern "C" void kernel_launch(void* const* d_in, const int* in_sizes, int n_in,
                              void* d_out, int out_size, void* d_ws, size_t ws_size,
                              hipStream_t stream)
{
    const float* eouts = (const float*)d_in[0];
    const float* W     = (const float*)d_in[1];
    const float* bias  = (const float*)d_in[2];
    const int*   ys    = (const int*)d_in[3];
    const int*   elens = (const int*)d_in[4];
    const int*   ylens = (const int*)d_in[5];
    float* out = (float*)d_out;

    char* ws = (char*)d_ws;
    unsigned short* eb = (unsigned short*)ws;                  // 32,768,000 B
    unsigned short* wb = (unsigned short*)(ws + 32768000);     //  2,097,152 B
    float* Srow        = (float*)(ws + 34865152);              //    128,000 B
    float* g           = (float*)(ws + 34993152);              // 13,312,000 B

    prep_kernel<<<17057, 256, 0, stream>>>(eouts, W, eb, wb, Srow, out);
    gemm_lse_kernel<<<dim3(16, 250), 256, 0, stream>>>(eb, wb, bias, Srow);
    gather_mfma_kernel<<<dim3(8, 32), 256, 0, stream>>>(eb, wb, bias, ys, Srow, g);
    ctc_dp_kernel<<<B_, 64, 0, stream>>>(g, ys, elens, ylens, out);
}

// Round 11
// 304.801 us; speedup vs baseline: 1.5921x; 1.2139x over previous
//
#include <hip/hip_runtime.h>
#include <hip/hip_bf16.h>

#define B_ 32
#define T_ 1000
#define H_ 512
#define V_ 2048
#define L_ 100
#define M_ (B_*T_)          // 32000 rows
#define GSTRIDE 104         // p_ext row stride (floats): [0]=blank, [2+l]=label l
#define LOG2E 1.4426950408889634f
#define LSE_SHIFT 48.0f
#define BIAS60 1.152921504606847e18f   // 2^60

typedef __attribute__((ext_vector_type(8))) short bf16x8;
typedef __attribute__((ext_vector_type(4))) float f32x4;

#define AS_G(p)  ((const __attribute__((address_space(1))) unsigned int*)(p))
#define AS_L(p)  ((__attribute__((address_space(3))) unsigned int*)(p))

__device__ __forceinline__ unsigned short f2bf(float x) {
    unsigned int u; __builtin_memcpy(&u, &x, 4);
    unsigned int r = (u + 0x7fffu + ((u >> 16) & 1u)) >> 16;   // RNE
    return (unsigned short)r;
}

// DPP helpers (verified R3/R5/R9).
__device__ __forceinline__ float dpp_shr1(float x) {          // lane i <- lane i-1, lane0 <- 0
    int r = __builtin_amdgcn_update_dpp(0, __builtin_bit_cast(int, x), 0x138, 0xf, 0xf, false);
    return __builtin_bit_cast(float, r);
}
template<int CTRL>
__device__ __forceinline__ float fmax_dpp(float x) {          // zero-fill ok: operands >= 0
    int s = __builtin_amdgcn_update_dpp(0, __builtin_bit_cast(int, x), CTRL, 0xf, 0xf, false);
    return fmaxf(x, __builtin_bit_cast(float, s));
}
__device__ __forceinline__ float wave_max_nonneg(float x) {   // max over 64 lanes, broadcast
    x = fmax_dpp<0x111>(x);
    x = fmax_dpp<0x112>(x);
    x = fmax_dpp<0x114>(x);
    x = fmax_dpp<0x118>(x);
    x = fmax_dpp<0x142>(x);
    x = fmax_dpp<0x143>(x);
    return __builtin_bit_cast(float, __builtin_amdgcn_readlane(__builtin_bit_cast(int, x), 63));
}

// ---------------------------------------------------------------------------
// Kernel 0: zero out + Srow, convert eouts/W fp32 -> bf16 into ws
// ---------------------------------------------------------------------------
__global__ __launch_bounds__(256) void prep_kernel(
        const float* __restrict__ eouts, const float* __restrict__ W,
        unsigned short* __restrict__ eb, unsigned short* __restrict__ wb,
        float* __restrict__ Srow, float* __restrict__ out)
{
    const int E4 = M_*H_/4;      // 4,096,000
    const int W4 = V_*H_/4;      //   262,144
    const int S4 = M_/4;         //     8,000
    int idx = blockIdx.x*256 + threadIdx.x;
    if (idx == 0) out[0] = 0.f;
    if (idx < E4) {
        float4 v = ((const float4*)eouts)[idx];
        ushort4 o; o.x=f2bf(v.x); o.y=f2bf(v.y); o.z=f2bf(v.z); o.w=f2bf(v.w);
        ((ushort4*)eb)[idx] = o;
    } else if (idx < E4 + W4) {
        int j = idx - E4;
        float4 v = ((const float4*)W)[j];
        ushort4 o; o.x=f2bf(v.x); o.y=f2bf(v.y); o.z=f2bf(v.z); o.w=f2bf(v.w);
        ((ushort4*)wb)[j] = o;
    } else if (idx < E4 + W4 + S4) {
        int j = idx - E4 - W4;
        ((float4*)Srow)[j] = make_float4(0.f,0.f,0.f,0.f);
    }
}

// ---------------------------------------------------------------------------
// Kernel 1: bf16 MFMA GEMM + fused row-sum of 2^(z*log2e - 48).
// 128x128 tile, BK=64, global_load_lds x16, XOR bank swizzle (R9-validated:
// SQ_LDS_BANK_CONFLICT == 0). chunk c of tile-row R at R*64 + (c^(R&7))*8.
// ---------------------------------------------------------------------------
__global__ __launch_bounds__(256) void gemm_lse_kernel(
        const unsigned short* __restrict__ eb, const unsigned short* __restrict__ wb,
        const float* __restrict__ bias, float* __restrict__ Srow)
{
    __shared__ __align__(16) unsigned short As[128*64];
    __shared__ __align__(16) unsigned short Bs[128*64];
    __shared__ float rs[128];
    const int tid  = threadIdx.x;
    const int w    = tid >> 6;
    const int lane = tid & 63;
    const int m    = lane & 15;
    const int q    = lane >> 4;
    const int wrow = w >> 1;
    const int wcol = w & 1;
    const int nbase = blockIdx.x * 128;
    const int mbase = blockIdx.y * 128;
    if (tid < 128) rs[tid] = 0.f;

    const int rbase = w*32 + (lane >> 3);
    const int k8    = (((lane & 7) ^ ((lane >> 3) & 7)) * 8);   // swizzled chunk
    const int rl    = m & 7;                                    // row&7 for frags

    f32x4 acc[4][4];
    #pragma unroll
    for (int i=0;i<4;i++)
        #pragma unroll
        for (int j=0;j<4;j++) acc[i][j] = (f32x4){0.f,0.f,0.f,0.f};

    for (int kc = 0; kc < 8; ++kc) {
        __syncthreads();
        #pragma unroll
        for (int j = 0; j < 4; ++j) {
            const unsigned short* ga = eb + (size_t)(mbase + rbase + j*8)*H_ + kc*64 + k8;
            __builtin_amdgcn_global_load_lds(AS_G(ga), AS_L(As + (w*4+j)*512), 16, 0, 0);
            const unsigned short* gw = wb + (size_t)(nbase + rbase + j*8)*H_ + kc*64 + k8;
            __builtin_amdgcn_global_load_lds(AS_G(gw), AS_L(Bs + (w*4+j)*512), 16, 0, 0);
        }
        __syncthreads();
        #pragma unroll
        for (int kk = 0; kk < 2; ++kk) {
            const int sw = ((kk*4 + q) ^ rl) * 8;
            bf16x8 af[4], bfr[4];
            #pragma unroll
            for (int mi=0;mi<4;mi++)
                af[mi] = *(const bf16x8*)(As + (wrow*8 + mi*2 + (m>>3))*512 + rl*64 + sw);
            #pragma unroll
            for (int ni=0;ni<4;ni++)
                bfr[ni] = *(const bf16x8*)(Bs + (wcol*8 + ni*2 + (m>>3))*512 + rl*64 + sw);
            #pragma unroll
            for (int mi=0;mi<4;mi++)
                #pragma unroll
                for (int ni=0;ni<4;ni++)
                    acc[mi][ni] = __builtin_amdgcn_mfma_f32_16x16x32_bf16(
                        af[mi], bfr[ni], acc[mi][ni], 0, 0, 0);
        }
    }

    float bv[4];
    #pragma unroll
    for (int ni=0;ni<4;ni++) bv[ni] = bias[nbase + wcol*64 + ni*16 + m];
    #pragma unroll
    for (int mi=0;mi<4;mi++) {
        #pragma unroll
        for (int r=0;r<4;r++) {
            float s = 0.f;
            #pragma unroll
            for (int ni=0;ni<4;ni++)
                s += exp2f((acc[mi][ni][r] + bv[ni]) * LOG2E - LSE_SHIFT);
            s += __shfl_xor(s, 1);
            s += __shfl_xor(s, 2);
            s += __shfl_xor(s, 4);
            s += __shfl_xor(s, 8);
            if (m == 0) atomicAdd(&rs[wrow*64 + mi*16 + q*4 + r], s);
        }
    }
    __syncthreads();
    if (tid < 128) atomicAdd(&Srow[mbase + tid], rs[tid]);
}

// ---------------------------------------------------------------------------
// Kernel 2: gather ext-label probs via MFMA (B-rows gathered by vocab id),
// same XOR bank swizzle as kernel 1.
// ---------------------------------------------------------------------------
__global__ __launch_bounds__(256) void gather_mfma_kernel(
        const unsigned short* __restrict__ eb, const unsigned short* __restrict__ wb,
        const float* __restrict__ bias, const int* __restrict__ ys,
        const float* __restrict__ Srow, float* __restrict__ g)
{
    __shared__ __align__(16) unsigned short As[128*64];
    __shared__ __align__(16) unsigned short Bs[128*64];
    __shared__ float ls[128];
    const int tid  = threadIdx.x;
    const int w    = tid >> 6;
    const int lane = tid & 63;
    const int m    = lane & 15;
    const int q    = lane >> 4;
    const int wrow = w >> 1;
    const int wcol = w & 1;
    const int b    = blockIdx.y;
    const int tb   = blockIdx.x * 128;

    if (tid < 128) {
        int t = tb + tid;
        ls[tid] = (t < T_) ? (LSE_SHIFT + log2f(Srow[b*T_ + t])) : 0.f;
    }

    const int rbase = w*32 + (lane >> 3);
    const int k8    = (((lane & 7) ^ ((lane >> 3) & 7)) * 8);
    const int rl    = m & 7;

    int vrow[4];
    #pragma unroll
    for (int j=0;j<4;++j) {
        int labr = rbase + j*8;
        vrow[j] = (labr == 0 || labr > L_) ? 0 : ys[b*L_ + labr - 1];
    }
    int labc[4]; float bv[4];
    #pragma unroll
    for (int ni=0;ni<4;++ni) {
        int lab = wcol*64 + ni*16 + m;
        labc[ni] = lab;
        int v = (lab == 0 || lab > L_) ? 0 : ys[b*L_ + lab - 1];
        bv[ni] = bias[v];
    }

    f32x4 acc[4][4];
    #pragma unroll
    for (int i=0;i<4;i++)
        #pragma unroll
        for (int j=0;j<4;j++) acc[i][j] = (f32x4){0.f,0.f,0.f,0.f};

    for (int kc = 0; kc < 8; ++kc) {
        __syncthreads();
        #pragma unroll
        for (int j = 0; j < 4; ++j) {
            const unsigned short* ga = eb + (size_t)(b*T_ + tb + rbase + j*8)*H_ + kc*64 + k8;
            __builtin_amdgcn_global_load_lds(AS_G(ga), AS_L(As + (w*4+j)*512), 16, 0, 0);
            const unsigned short* gw = wb + (size_t)vrow[j]*H_ + kc*64 + k8;
            __builtin_amdgcn_global_load_lds(AS_G(gw), AS_L(Bs + (w*4+j)*512), 16, 0, 0);
        }
        __syncthreads();
        #pragma unroll
        for (int kk = 0; kk < 2; ++kk) {
            const int sw = ((kk*4 + q) ^ rl) * 8;
            bf16x8 af[4], bfr[4];
            #pragma unroll
            for (int mi=0;mi<4;mi++)
                af[mi] = *(const bf16x8*)(As + (wrow*8 + mi*2 + (m>>3))*512 + rl*64 + sw);
            #pragma unroll
            for (int ni=0;ni<4;ni++)
                bfr[ni] = *(const bf16x8*)(Bs + (wcol*8 + ni*2 + (m>>3))*512 + rl*64 + sw);
            #pragma unroll
            for (int mi=0;mi<4;mi++)
                #pragma unroll
                for (int ni=0;ni<4;ni++)
                    acc[mi][ni] = __builtin_amdgcn_mfma_f32_16x16x32_bf16(
                        af[mi], bfr[ni], acc[mi][ni], 0, 0, 0);
        }
    }

    #pragma unroll
    for (int mi=0;mi<4;mi++) {
        #pragma unroll
        for (int r=0;r<4;r++) {
            int trow = wrow*64 + mi*16 + q*4 + r;
            int t = tb + trow;
            float l2 = ls[trow];
            #pragma unroll
            for (int ni=0;ni<4;ni++) {
                if (t < T_ && labc[ni] <= L_) {
                    float p = exp2f((acc[mi][ni][r] + bv[ni]) * LOG2E - l2);
                    int off = (labc[ni] == 0) ? 0 : labc[ni] + 1;
                    g[(size_t)(b*T_ + t)*GSTRIDE + off] = p;
                }
            }
        }
    }
}

// ---------------------------------------------------------------------------
// Kernel 3: CTC forward DP — producer/consumer waves, barrier-ordered.
// Wave 1 (producer) DMAs burst k+1 into set (k+1)&1 while wave 0 (consumer)
// stages+DPs burst k from set k&1; __syncthreads() at iter end both drains
// the producer's DMA (per-wave vmcnt at barrier) and orders the consumer's
// reads before the next overwrite. LDS ops cannot be scheduled across a
// barrier, so the R6-R10 read-sinking WAR hazard is impossible here.
// Renorm: full restore to 2^60 every 8 steps (R5-proven), exact accounting.
// Masks folded at staging (R8 fix). Burst k = pairs 8k..8k+7 = rows 16k..16k+15.
// ---------------------------------------------------------------------------
__global__ __launch_bounds__(128, 1) void ctc_dp_kernel(
        const float* __restrict__ g, const int* __restrict__ ys,
        const int* __restrict__ elens, const int* __restrict__ ylens,
        float* __restrict__ out)
{
    __shared__ __align__(16) float ring[2*2048];   // 2 sets x 8 pair-slots x 1KB
    const int b    = blockIdx.x;
    const int tid  = threadIdx.x;
    const int wv   = tid >> 6;
    const int lane = tid & 63;
    const float* gb = g + (size_t)b * T_ * GSTRIDE;
    const int ylen = ylens[b];
    const int elen = elens[b];
    const int kmax = (elen - 1) >> 4;

    // consumer-side constants (wave 1 computes unused copies; harmless)
    const int Sv   = 2*ylen + 1;
    const int s0   = 4*lane;
    const float msk0 = (s0   < Sv) ? 1.f : 0.f;
    const float msk1 = (s0+1 < Sv) ? 1.f : 0.f;
    const float msk2 = (s0+2 < Sv) ? 1.f : 0.f;
    const float msk3 = (s0+3 < Sv) ? 1.f : 0.f;
    const int l0 = 2*lane, l1 = 2*lane + 1;
    int i0 = min(max(l0,1), L_-1);
    int i1 = min(l1, L_-1);
    const float sk1 = (l0 >= 1 && l0 < L_ && ys[b*L_+i0] != ys[b*L_+i0-1]) ? 1.f : 0.f;
    const float sk3 = (l1 < L_        && ys[b*L_+i1] != ys[b*L_+i1-1]) ? 1.f : 0.f;

    float a0 = 0.f, a1 = 0.f, a2 = 0.f, a3 = 0.f, C2 = 0.f;
    if (wv == 0) {
        a0 = (lane == 0) ? gb[0] : 0.f;     // t=0 init
        a1 = (lane == 0) ? gb[2] : 0.f;
    } else {
        // producer prologue: burst 0 -> set 0 (pairs 0..7 = rows 0..15)
        #pragma unroll
        for (int s = 0; s < 8; ++s) {
            int srow = min(2*s, T_-2);
            __builtin_amdgcn_global_load_lds(AS_G(gb + (size_t)srow*GSTRIDE + 4*lane),
                                             AS_L(ring + s*256), 16, 0, 0);
        }
    }

    auto dpstep = [&](float p0, float p1, float p2, float p3) {
        float um1 = dpp_shr1(a3);
        float n0 = a0 + um1;
        float n1 = a1 + a0 + sk1*um1;
        float n2 = a2 + a1;
        float n3 = a3 + a2 + sk3*a1;
        a0 = n0*p0; a1 = n1*p1; a2 = n2*p2; a3 = n3*p3;
    };
    auto renorm = [&]() {   // full restore to ~2^60, exactly accounted
        float mm = wave_max_nonneg(fmaxf(fmaxf(a0,a1), fmaxf(a2,a3)));
        if (mm > 0.f) {
            float rr = fminf(__fdividef(BIAS60, mm), 3.0e38f);
            C2 -= __log2f(rr);
            a0 *= rr; a1 *= rr; a2 *= rr; a3 *= rr;
        }
    };

    __syncthreads();                                  // burst 0 landed

    for (int k = 0; k <= kmax; ++k) {
        if (wv == 1) {
            if (k < kmax) {                           // burst k+1 -> set (k+1)&1
                float* dset = ring + ((k+1) & 1)*2048;
                int pbase = 8*(k + 1);
                #pragma unroll
                for (int s = 0; s < 8; ++s) {
                    int srow = min(2*(pbase + s), T_-2);
                    __builtin_amdgcn_global_load_lds(AS_G(gb + (size_t)srow*GSTRIDE + 4*lane),
                                                     AS_L(dset + s*256), 16, 0, 0);
                }
            }
        } else {
            const float* sb = ring + (k & 1)*2048;
            float P0[16], P1[16], P2[16], P3[16];     // masks folded at staging
            #pragma unroll
            for (int s = 0; s < 8; ++s) {
                const float* slot = sb + s*256;
                float pb0 = slot[0];
                float pb1 = slot[104];
                float2 lo = *(const float2*)(slot + 2  + 2*lane);
                float2 hi = *(const float2*)(slot + 106 + 2*lane);
                P0[2*s]   = pb0*msk0; P1[2*s]   = lo.x*msk1;
                P2[2*s]   = pb0*msk2; P3[2*s]   = lo.y*msk3;
                P0[2*s+1] = pb1*msk0; P1[2*s+1] = hi.x*msk1;
                P2[2*s+1] = pb1*msk2; P3[2*s+1] = hi.y*msk3;
            }
            const int t0 = 16*k;
            #pragma unroll
            for (int j = 0; j < 16; ++j) {
                int t = t0 + j;
                if (t > 0 && t < elen)
                    dpstep(P0[j], P1[j], P2[j], P3[j]);
                if ((j & 7) == 7) renorm();
            }
        }
        __syncthreads();                              // drain burst k+1; order reads
    }

    if (wv == 0) {
        int sA = 2*ylen, sB = sA - 1;
        float vA = __shfl((sA & 2) ? a2 : a0, sA >> 2);
        float vB = __shfl((sB & 2) ? a3 : a1, sB >> 2);
        if (lane == 0) {
            float sum = vA + vB;
            float loss = 0.f;
            if (sum > 0.f) {
                loss = -(log2f(sum) + C2) * 0.6931471805599453f;
                if (!(loss < 5e9f)) loss = 0.f;         // zero_infinity
            }
            atomicAdd(out, loss * (1.0f/B_));
        }
    }
}

// ---------------------------------------------------------------------------
extern "C" void kernel_launch(void* const* d_in, const int* in_sizes, int n_in,
                              void* d_out, int out_size, void* d_ws, size_t ws_size,
                              hipStream_t stream)
{
    const float* eouts = (const float*)d_in[0];
    const float* W     = (const float*)d_in[1];
    const float* bias  = (const float*)d_in[2];
    const int*   ys    = (const int*)d_in[3];
    const int*   elens = (const int*)d_in[4];
    const int*   ylens = (const int*)d_in[5];
    float* out = (float*)d_out;

    char* ws = (char*)d_ws;
    unsigned short* eb = (unsigned short*)ws;                  // 32,768,000 B
    unsigned short* wb = (unsigned short*)(ws + 32768000);     //  2,097,152 B
    float* Srow        = (float*)(ws + 34865152);              //    128,000 B
    float* g           = (float*)(ws + 34993152);              // 13,312,000 B

    prep_kernel<<<17057, 256, 0, stream>>>(eouts, W, eb, wb, Srow, out);
    gemm_lse_kernel<<<dim3(16, 250), 256, 0, stream>>>(eb, wb, bias, Srow);
    gather_mfma_kernel<<<dim3(8, 32), 256, 0, stream>>>(eb, wb, bias, ys, Srow, g);
    ctc_dp_kernel<<<B_, 128, 0, stream>>>(g, ys, elens, ylens, out);
}